// Round 21
// baseline (332.122 us; speedup 1.0000x reference)
//
#include <hip/hip_runtime.h>
#include <hip/hip_bf16.h>
#include <math.h>

// SplineCNN on MI355X — round 21 (R20 + DEPTH=2 for ALL layers + pool unroll).
// R20 = best known (327us). Changes: (a) L3 stage-1 now also uses the 2-deep
// gather pipeline (both chunks' 32 gathers in flight before compute at TC=2;
// af ring ~+16 VGPR, fits under the 128 cap — WRITE_SIZE is the spill canary);
// (b) pool_kernel processes 4 nodes per iteration with independent loads
// (was a serial ~98-iteration load->add chain per wave).

typedef __attribute__((ext_vector_type(8))) short bf16x8;
typedef __attribute__((ext_vector_type(4))) float f32x4;

constexpr int SCAN_CHUNK = 2048;

__device__ __forceinline__ unsigned short f2bf(float f) {
    union { float f; unsigned u; } v; v.f = f;
    return (unsigned short)((v.u + 0x7fffu + ((v.u >> 16) & 1u)) >> 16);
}
__device__ __forceinline__ float bf2f(unsigned short h) {
    union { unsigned u; float f; } v; v.u = ((unsigned)h) << 16;
    return v.f;
}
__device__ __forceinline__ int pairaddr(int kk) {
    int slice = kk >> 5;
    return (slice >> 1) * 72 + (slice & 1) * 32 + (kk & 31);
}

// ---------------------------------------------------------------- preprocessing

__global__ void hist_kernel(const int* __restrict__ ei, int* __restrict__ deg, int E) {
    int e = blockIdx.x * blockDim.x + threadIdx.x;
    if (e < E) atomicAdd(&deg[ei[E + e]], 1);
}

__global__ __launch_bounds__(256) void scan1_kernel(const int* __restrict__ deg,
                                                    int* __restrict__ blockSums, int n) {
    __shared__ int wsum[4];
    int tid = threadIdx.x, lane = tid & 63, wave = tid >> 6;
    int idx0 = blockIdx.x * SCAN_CHUNK + tid * 8;
    int s = 0;
    #pragma unroll
    for (int u = 0; u < 8; ++u) {
        int id = idx0 + u;
        int d = (id < n) ? deg[id] : 0;
        s += (d + 7) & ~7;
    }
    #pragma unroll
    for (int off = 1; off < 64; off <<= 1) s += __shfl_xor(s, off);
    if (lane == 0) wsum[wave] = s;
    __syncthreads();
    if (tid == 0) blockSums[blockIdx.x] = wsum[0] + wsum[1] + wsum[2] + wsum[3];
}

__global__ void scan2_kernel(int* __restrict__ blockSums, int* __restrict__ row_start,
                             int nb, int n) {
    int lane = threadIdx.x & 63;
    int v = (lane < nb) ? blockSums[lane] : 0;
    int inc = v;
    #pragma unroll
    for (int off = 1; off < 64; off <<= 1) {
        int t = __shfl_up(inc, off);
        if (lane >= off) inc += t;
    }
    if (lane < nb) blockSums[lane] = inc - v;
    if (lane == 63) row_start[n] = inc;
}

__global__ __launch_bounds__(256) void scan3_kernel(const int* __restrict__ deg,
                                                    const int* __restrict__ blockSums,
                                                    int* __restrict__ row_start,
                                                    int* __restrict__ cursor,
                                                    float* __restrict__ invdeg, int n) {
    __shared__ int wsum[4];
    int tid = threadIdx.x, lane = tid & 63, wave = tid >> 6;
    int carry = blockSums[blockIdx.x];
    int idx0 = blockIdx.x * SCAN_CHUNK + tid * 8;
    int v[8], pre[8];
    int s = 0;
    #pragma unroll
    for (int u = 0; u < 8; ++u) {
        int id = idx0 + u;
        int d = (id < n) ? deg[id] : 0;
        v[u] = d;
        pre[u] = s;
        s += (d + 7) & ~7;
    }
    int inc = s;
    #pragma unroll
    for (int off = 1; off < 64; off <<= 1) {
        int t = __shfl_up(inc, off);
        if (lane >= off) inc += t;
    }
    if (lane == 63) wsum[wave] = inc;
    __syncthreads();
    int woff = 0;
    for (int w2 = 0; w2 < wave; ++w2) woff += wsum[w2];
    int eb = carry + woff + inc - s;
    #pragma unroll
    for (int u = 0; u < 8; ++u) {
        int id = idx0 + u;
        if (id < n) {
            int rs = eb + pre[u];
            row_start[id] = rs;
            cursor[id] = rs;
            invdeg[id] = 1.0f / fmaxf((float)v[u], 1.0f);
        }
    }
}

// SoA record: basisB[pos] = {b0|b1<<16, b2|b3<<16} bf16, metaB[pos] = src | i00<<20
__global__ void scatter_kernel(const int* __restrict__ ei, const float* __restrict__ pseudo,
                               const float* __restrict__ invdeg, int* __restrict__ cursor,
                               uint2* __restrict__ basisB, unsigned* __restrict__ metaB, int E) {
    int e = blockIdx.x * blockDim.x + threadIdx.x;
    if (e >= E) return;
    int src = ei[e], dst = ei[E + e];
    float p0 = pseudo[2 * e], p1 = pseudo[2 * e + 1];
    float v0 = fminf(fmaxf(p0, 0.f), 1.f) * 4.f;
    float v1 = fminf(fmaxf(p1, 0.f), 1.f) * 4.f;
    int k00 = min((int)floorf(v0), 3);
    int k01 = min((int)floorf(v1), 3);
    float f0 = v0 - (float)k00, f1 = v1 - (float)k01;
    float g0 = 1.f - f0, g1 = 1.f - f1;
    float sc = invdeg[dst];
    int i00 = k00 * 5 + k01;
    int pos = atomicAdd(&cursor[dst], 1);
    uint2 b;
    b.x = (unsigned)f2bf(g0 * g1 * sc) | ((unsigned)f2bf(g0 * f1 * sc) << 16);
    b.y = (unsigned)f2bf(f0 * g1 * sc) | ((unsigned)f2bf(f0 * f1 * sc) << 16);
    basisB[pos] = b;
    metaB[pos] = (unsigned)src | ((unsigned)i00 << 20);
}

// Fragment-major Wt: WtF[((s*NT + nt)*64 + lane)*8 + e] = W_logical[o][kk]
template <int Cin, int Cout, int KW>
__global__ void wprep_kernel(const float* __restrict__ W, const float* __restrict__ root,
                             unsigned short* __restrict__ WtF) {
    constexpr int NT = Cout / 16;
    int idx = blockIdx.x * 256 + threadIdx.x;
    if (idx >= Cout * KW) return;
    int e = idx & 7;
    int lane = (idx >> 3) & 63;
    int sn = idx >> 9;
    int s = sn / NT, nt = sn - s * NT;
    int r16 = lane & 15, g8 = lane >> 4;
    int o = nt * 16 + r16;
    int kk = s * 32 + g8 * 8 + e;
    float v = 0.f;
    if (kk < 26 * Cin) {
        int k = kk / Cin, i = kk - k * Cin;
        v = (k < 25) ? W[(k * Cin + i) * Cout + o] : root[i * Cout + o];
    }
    WtF[idx] = f2bf(v);
}

// ---------------------------------------------------------------- fused layer

template <int Cin, int Cout, bool F32IN>
__global__ __launch_bounds__(512, 4) void layer_kernel(
        const void* __restrict__ xin_, const unsigned short* __restrict__ WtF,
        const float* __restrict__ bias, const int* __restrict__ row_start,
        const int* __restrict__ row_end, const uint2* __restrict__ basisG,
        const unsigned* __restrict__ metaG, unsigned short* __restrict__ xout,
        int nNodes) {
    constexpr int T = 16;
    constexpr int SLICES = (26 * Cin + 31) / 32;
    constexpr int NPAIR = (SLICES + 1) / 2;
    constexpr int ST = NPAIR * 72 + 8;          // ushort elems per node row
    constexpr int MT = (Cin + 15) / 16;
    constexpr int NT_B = Cout / 16;
    constexpr int W8 = 8 / NT_B;
    constexpr int RS = Cout + 4;
    constexpr int BSZ = 32 * 34;                // ushorts per wave B matrix

    __shared__ __align__(16) unsigned short acc[T * ST];
    __shared__ __align__(16) unsigned short Ball[8 * BSZ];

    const int tid = threadIdx.x;
    const int node0 = blockIdx.x * T;
    const int wave = tid >> 6, lane = tid & 63;
    const int r16 = lane & 15, g8 = lane >> 4;   // g8 in 0..3
    const float* xf = (const float*)xin_;
    const unsigned short* xb = (const unsigned short*)xin_;

    // ---- zero acc
    {
        uint4 z = make_uint4(0u, 0u, 0u, 0u);
        for (int p = tid; p < T * ST / 8; p += 512) ((uint4*)acc)[p] = z;
    }
    __syncthreads();
    // ---- self features at k=25
    for (int p = tid; p < T * Cin; p += 512) {
        int t = p / Cin, i = p - t * Cin;
        int n = node0 + t;
        if (n < nNodes) {
            unsigned short v = F32IN ? f2bf(xf[n * Cin + i]) : xb[n * Cin + i];
            acc[t * ST + pairaddr(25 * Cin + i)] = v;
        }
    }

    // ---- stage-1: 2 nodes per wave, 2-deep pipelined 32-edge virtual chunks
    unsigned short* Bw = Ball + wave * BSZ;
    {
        const int t0 = wave, t1 = wave + 8;
        const int na = node0 + t0, nb = node0 + t1;
        int eb0 = 0, ee0 = 0, eb1 = 0, ee1 = 0;
        if (na < nNodes) { eb0 = row_start[na]; ee0 = row_end[na]; }
        if (nb < nNodes) { eb1 = row_start[nb]; ee1 = row_end[nb]; }
        const int nc0 = (ee0 - eb0 + 31) >> 5;
        const int nc1 = (ee1 - eb1 + 31) >> 5;
        const int TC = nc0 + nc1;

        if (TC > 0) {
            auto info = [&](int vc, int& base, int& ee) {
                bool first = vc < nc0;
                int c = first ? vc : vc - nc0;
                base = (first ? eb0 : eb1) + (c << 5);
                ee = first ? ee0 : ee1;
            };
            auto loadMeta = [&](int vc, uint4& a, uint4& b) {
                int base, ee;
                info(vc, base, ee);
                const uint4* p = (const uint4*)(metaG + base + g8 * 8);
                a = p[0];
                b = p[1];
            };
            auto gatherA = [&](const uint4& a, const uint4& b, bf16x8* af) {
                int s[8];
                s[0] = a.x & 0xFFFFF; s[1] = a.y & 0xFFFFF;
                s[2] = a.z & 0xFFFFF; s[3] = a.w & 0xFFFFF;
                s[4] = b.x & 0xFFFFF; s[5] = b.y & 0xFFFFF;
                s[6] = b.z & 0xFFFFF; s[7] = b.w & 0xFFFFF;
                #pragma unroll
                for (int mt = 0; mt < MT; ++mt) {
                    int col = (Cin >= 16) ? (mt * 16 + r16) : (r16 & (Cin - 1));
                    #pragma unroll
                    for (int j = 0; j < 8; ++j)
                        af[mt][j] = (short)(F32IN ? f2bf(xf[s[j] * Cin + col])
                                                  : xb[s[j] * Cin + col]);
                }
            };
            auto loadScat = [&](int vc, unsigned& bx, unsigned& by, int& i00,
                                bool& valid) {
                int base, ee;
                info(vc, base, ee);
                int e = base + (lane & 31);
                valid = (lane < 32) && (e < ee);
                uint2 bb = basisG[e];
                unsigned mm = metaG[e];
                bx = bb.x;
                by = bb.y;
                i00 = (int)(mm >> 20);
            };

            f32x4 d[MT][2];
            #pragma unroll
            for (int mt = 0; mt < MT; ++mt)
                #pragma unroll
                for (int nt = 0; nt < 2; ++nt)
                    d[mt][nt] = (f32x4){0.f, 0.f, 0.f, 0.f};

            auto spill = [&](int t) {
                #pragma unroll
                for (int nt = 0; nt < 2; ++nt) {
                    int k = nt * 16 + r16;
                    if (k < 25) {
                        #pragma unroll
                        for (int mt = 0; mt < MT; ++mt) {
                            int ch0 = mt * 16 + g8 * 4;
                            if (ch0 < Cin) {
                                unsigned p0 = (unsigned)f2bf(d[mt][nt][0]) |
                                              ((unsigned)f2bf(d[mt][nt][1]) << 16);
                                unsigned p1 = (unsigned)f2bf(d[mt][nt][2]) |
                                              ((unsigned)f2bf(d[mt][nt][3]) << 16);
                                *(uint2*)&acc[t * ST + pairaddr(k * Cin + ch0)] =
                                    make_uint2(p0, p1);
                            }
                        }
                    }
                }
                #pragma unroll
                for (int mt = 0; mt < MT; ++mt)
                    #pragma unroll
                    for (int nt = 0; nt < 2; ++nt)
                        d[mt][nt] = (f32x4){0.f, 0.f, 0.f, 0.f};
            };

            auto computeB = [&](unsigned bxC, unsigned byC, int i00C, bool vldC,
                                bf16x8* af) {
                uint4 z = make_uint4(0u, 0u, 0u, 0u);
                uint4* b4 = (uint4*)Bw;
                #pragma unroll
                for (int q = 0; q < 3; ++q) {
                    int p = lane + q * 64;
                    if (p < BSZ / 8) b4[p] = z;
                }
                if (vldC) {
                    int le = lane & 31;
                    Bw[le * 34 + i00C]     = (unsigned short)(bxC & 0xFFFFu);
                    Bw[le * 34 + i00C + 1] = (unsigned short)(bxC >> 16);
                    Bw[le * 34 + i00C + 5] = (unsigned short)(byC & 0xFFFFu);
                    Bw[le * 34 + i00C + 6] = (unsigned short)(byC >> 16);
                }
                #pragma unroll
                for (int nt = 0; nt < 2; ++nt) {
                    bf16x8 bfr;
                    #pragma unroll
                    for (int j = 0; j < 8; ++j)
                        bfr[j] = (short)Bw[(g8 * 8 + j) * 34 + nt * 16 + r16];
                    #pragma unroll
                    for (int mt = 0; mt < MT; ++mt)
                        d[mt][nt] = __builtin_amdgcn_mfma_f32_16x16x32_bf16(
                            af[mt], bfr, d[mt][nt], 0, 0, 0);
                }
            };

            // 2-deep gather pipeline (all layers)
            uint4 m2a, m2b;
            bf16x8 af0[MT], af1[MT], af2[MT];
            unsigned bxC, byC, bxN, byN;
            int i00C, i00N;
            bool vldC, vldN;
            {
                uint4 a, b;
                loadMeta(0, a, b);
                gatherA(a, b, af0);
                if (TC > 1) {
                    loadMeta(1, a, b);
                    gatherA(a, b, af1);
                }
                if (TC > 2) loadMeta(2, m2a, m2b);
            }
            loadScat(0, bxC, byC, i00C, vldC);

            for (int vc = 0; vc < TC; ++vc) {
                if (vc + 2 < TC) {
                    gatherA(m2a, m2b, af2);
                    if (vc + 3 < TC) loadMeta(vc + 3, m2a, m2b);
                }
                if (vc + 1 < TC) loadScat(vc + 1, bxN, byN, i00N, vldN);

                computeB(bxC, byC, i00C, vldC, af0);
                if (vc == nc0 - 1) spill(t0);

                #pragma unroll
                for (int mt = 0; mt < MT; ++mt) {
                    af0[mt] = af1[mt];
                    af1[mt] = af2[mt];
                }
                bxC = bxN; byC = byN; i00C = i00N; vldC = vldN;
            }
            if (nc1 > 0) spill(t1);
        }
    }
    __syncthreads();

    // ---- phase B: acc x WtF (fragment-major, contiguous 1KB loads), K-split W8
    const int q = wave / NT_B;
    const int nt = wave % NT_B;
    f32x4 db = {0.f, 0.f, 0.f, 0.f};
    {
        const unsigned short* ap = acc + r16 * ST;
        for (int s = q; s < SLICES; s += W8) {
            bf16x8 a8 = *(const bf16x8*)(ap + (s >> 1) * 72 + (s & 1) * 32 + g8 * 8);
            bf16x8 b8 = *(const bf16x8*)(WtF + ((size_t)(s * NT_B + nt) * 64 + lane) * 8);
            db = __builtin_amdgcn_mfma_f32_16x16x32_bf16(a8, b8, db, 0, 0, 0);
        }
    }
    __syncthreads();
    float* red = (float*)acc;
    if (q > 0) {
        #pragma unroll
        for (int j = 0; j < 4; ++j)
            red[((q - 1) * T + g8 * 4 + j) * RS + nt * 16 + r16] = db[j];
    }
    __syncthreads();
    if (q == 0) {
        const int o = nt * 16 + r16;
        const float bo = bias[o];
        #pragma unroll
        for (int j = 0; j < 4; ++j) {
            int row = g8 * 4 + j;
            int n = node0 + row;
            if (n < nNodes) {
                float v = db[j] + bo;
                #pragma unroll
                for (int q2 = 1; q2 < W8; ++q2)
                    v += red[((q2 - 1) * T + row) * RS + o];
                v = (v > 0.f) ? v : expm1f(v);
                xout[n * Cout + o] = f2bf(v);
            }
        }
    }
}

// ---------------------------------------------------------------- pooling + head

__global__ void pool_kernel(const unsigned short* __restrict__ h, const int* __restrict__ batch,
                            float* __restrict__ pooled, float* __restrict__ cnt, int n) {
    int gw = (blockIdx.x * blockDim.x + threadIdx.x) >> 6;
    int lane = threadIdx.x & 63;
    int nw = (gridDim.x * blockDim.x) >> 6;
    int per = (n + nw - 1) / nw;
    int n0 = gw * per, n1 = min(n0 + per, n);
    if (n0 >= n1) return;
    int cur = batch[n0];
    float s = 0.f, c = 0.f;
    int nn = n0;
    while (nn < n1) {
        int m = min(4, n1 - nn);
        float v[4];
        int b[4];
        #pragma unroll
        for (int u = 0; u < 4; ++u) {
            int id = (u < m) ? (nn + u) : (n1 - 1);
            b[u] = batch[id];
            v[u] = bf2f(h[(size_t)id * 64 + lane]);
        }
        #pragma unroll
        for (int u = 0; u < 4; ++u) {
            if (u < m) {
                if (b[u] != cur) {
                    atomicAdd(&pooled[cur * 64 + lane], s);
                    if (lane == 0) atomicAdd(&cnt[cur], c);
                    s = 0.f; c = 0.f; cur = b[u];
                }
                s += v[u];
                c += 1.f;
            }
        }
        nn += 4;
    }
    atomicAdd(&pooled[cur * 64 + lane], s);
    if (lane == 0) atomicAdd(&cnt[cur], c);
}

// One wave per graph: lane j<30 computes logit_j; shfl reductions for log-softmax.
__global__ __launch_bounds__(64) void head_kernel(const float* __restrict__ pooled,
                                                  const float* __restrict__ cnt,
                                                  const float* __restrict__ fcw,
                                                  const float* __restrict__ fcb,
                                                  float* __restrict__ outp, int G) {
    int g = blockIdx.x;
    int j = threadIdx.x;
    if (g >= G) return;
    float inv = 1.f / fmaxf(cnt[g], 1.f);
    float s = -1e30f;
    if (j < 30) {
        s = fcb[j];
        for (int i = 0; i < 64; ++i)
            s += pooled[g * 64 + i] * inv * fcw[i * 30 + j];
    }
    float m = s;
    #pragma unroll
    for (int off = 1; off < 64; off <<= 1) m = fmaxf(m, __shfl_xor(m, off));
    float e = (j < 30) ? expf(s - m) : 0.f;
    float lse = e;
    #pragma unroll
    for (int off = 1; off < 64; off <<= 1) lse += __shfl_xor(lse, off);
    lse = logf(lse);
    if (j < 30) outp[g * 30 + j] = s - m - lse;
}

// ---------------------------------------------------------------- launch

extern "C" void kernel_launch(void* const* d_in, const int* in_sizes, int n_in,
                              void* d_out, int out_size, void* d_ws, size_t ws_size,
                              hipStream_t stream) {
    const float* x = (const float*)d_in[0];
    const int* ei = (const int*)d_in[1];
    const float* ps = (const float*)d_in[2];
    const int* batch = (const int*)d_in[3];
    const float *w1 = (const float*)d_in[4], *r1 = (const float*)d_in[5], *b1 = (const float*)d_in[6];
    const float *w2 = (const float*)d_in[7], *r2 = (const float*)d_in[8], *b2 = (const float*)d_in[9];
    const float *w3 = (const float*)d_in[10], *r3 = (const float*)d_in[11], *b3 = (const float*)d_in[12];
    const float *fcw = (const float*)d_in[13], *fcb = (const float*)d_in[14];
    float* outp = (float*)d_out;

    const int nN = in_sizes[0] / 8;  // 50000
    const int E = in_sizes[1] / 2;   // 800000
    const int G = out_size / 30;     // 128
    const int EP = E + 8 * nN + 64;  // padded edge capacity
    const int NSB = (nN + SCAN_CHUNK - 1) / SCAN_CHUNK;   // scan blocks (25 <= 64)

    char* wsb = (char*)d_ws;
    size_t off = 0;
    auto alloc = [&](size_t b) -> char* {
        char* p = wsb + off;
        off = (off + b + 255) & ~(size_t)255;
        return p;
    };
    int* deg = (int*)alloc((size_t)nN * 4);
    int* row_start = (int*)alloc((size_t)(nN + 1) * 4);
    int* cursor = (int*)alloc((size_t)nN * 4);
    float* invdeg = (float*)alloc((size_t)nN * 4);
    int* blockSums = (int*)alloc((size_t)64 * 4);
    uint2* basisB = (uint2*)alloc((size_t)EP * 8);
    unsigned* metaB = (unsigned*)alloc((size_t)EP * 4);
    unsigned short* wt1 = (unsigned short*)alloc((size_t)32 * 224 * 2);
    unsigned short* wt2 = (unsigned short*)alloc((size_t)64 * 832 * 2);
    unsigned short* wt3 = (unsigned short*)alloc((size_t)64 * 1664 * 2);
    unsigned short* h1 = (unsigned short*)alloc((size_t)nN * 32 * 2);
    unsigned short* h2 = (unsigned short*)alloc((size_t)nN * 64 * 2);
    unsigned short* h3 = (unsigned short*)alloc((size_t)nN * 64 * 2);
    float* pooled = (float*)alloc((size_t)G * 64 * 4);
    float* cnt = (float*)alloc((size_t)G * 4);
    (void)ws_size;

    hipMemsetAsync(deg, 0, (size_t)nN * 4, stream);
    hipMemsetAsync(metaB, 0, (size_t)EP * 4, stream);   // pad metas -> src 0 (safe)
    hipMemsetAsync(pooled, 0, (size_t)G * 64 * 4, stream);
    hipMemsetAsync(cnt, 0, (size_t)G * 4, stream);

    int ebk = (E + 255) / 256;
    hist_kernel<<<ebk, 256, 0, stream>>>(ei, deg, E);
    scan1_kernel<<<NSB, 256, 0, stream>>>(deg, blockSums, nN);
    scan2_kernel<<<1, 64, 0, stream>>>(blockSums, row_start, NSB, nN);
    scan3_kernel<<<NSB, 256, 0, stream>>>(deg, blockSums, row_start, cursor, invdeg, nN);
    scatter_kernel<<<ebk, 256, 0, stream>>>(ei, ps, invdeg, cursor, basisB, metaB, E);
    wprep_kernel<8, 32, 224><<<(32 * 224 + 255) / 256, 256, 0, stream>>>(w1, r1, wt1);
    wprep_kernel<32, 64, 832><<<(64 * 832 + 255) / 256, 256, 0, stream>>>(w2, r2, wt2);
    wprep_kernel<64, 64, 1664><<<(64 * 1664 + 255) / 256, 256, 0, stream>>>(w3, r3, wt3);

    int nb = (nN + 15) / 16;
    layer_kernel<8, 32, true><<<nb, 512, 0, stream>>>(
        x, wt1, b1, row_start, cursor, basisB, metaB, h1, nN);
    layer_kernel<32, 64, false><<<nb, 512, 0, stream>>>(
        h1, wt2, b2, row_start, cursor, basisB, metaB, h2, nN);
    layer_kernel<64, 64, false><<<nb, 512, 0, stream>>>(
        h2, wt3, b3, row_start, cursor, basisB, metaB, h3, nN);

    pool_kernel<<<128, 256, 0, stream>>>(h3, batch, pooled, cnt, nN);
    head_kernel<<<G, 64, 0, stream>>>(pooled, cnt, fcw, fcb, outp, G);
}

// Round 22
// 313.070 us; speedup vs baseline: 1.0609x; 1.0609x over previous
//
#include <hip/hip_runtime.h>
#include <hip/hip_bf16.h>
#include <math.h>

// SplineCNN on MI355X — round 22 (R20 layers + R21 pool unroll).
// R21 post-mortem: DEPTH=2 at MT=4 spilled (WRITE 6.25->79MB, L3 84->106us);
// revert layer pipeline policy to DEPTH=(MT<=2)?2:1. Keep R21's 4-wide pool
// unroll (saved ~17us) and R20's parallel head. Everything else = R20/R18.

typedef __attribute__((ext_vector_type(8))) short bf16x8;
typedef __attribute__((ext_vector_type(4))) float f32x4;

constexpr int SCAN_CHUNK = 2048;

__device__ __forceinline__ unsigned short f2bf(float f) {
    union { float f; unsigned u; } v; v.f = f;
    return (unsigned short)((v.u + 0x7fffu + ((v.u >> 16) & 1u)) >> 16);
}
__device__ __forceinline__ float bf2f(unsigned short h) {
    union { unsigned u; float f; } v; v.u = ((unsigned)h) << 16;
    return v.f;
}
__device__ __forceinline__ int pairaddr(int kk) {
    int slice = kk >> 5;
    return (slice >> 1) * 72 + (slice & 1) * 32 + (kk & 31);
}

// ---------------------------------------------------------------- preprocessing

__global__ void hist_kernel(const int* __restrict__ ei, int* __restrict__ deg, int E) {
    int e = blockIdx.x * blockDim.x + threadIdx.x;
    if (e < E) atomicAdd(&deg[ei[E + e]], 1);
}

__global__ __launch_bounds__(256) void scan1_kernel(const int* __restrict__ deg,
                                                    int* __restrict__ blockSums, int n) {
    __shared__ int wsum[4];
    int tid = threadIdx.x, lane = tid & 63, wave = tid >> 6;
    int idx0 = blockIdx.x * SCAN_CHUNK + tid * 8;
    int s = 0;
    #pragma unroll
    for (int u = 0; u < 8; ++u) {
        int id = idx0 + u;
        int d = (id < n) ? deg[id] : 0;
        s += (d + 7) & ~7;
    }
    #pragma unroll
    for (int off = 1; off < 64; off <<= 1) s += __shfl_xor(s, off);
    if (lane == 0) wsum[wave] = s;
    __syncthreads();
    if (tid == 0) blockSums[blockIdx.x] = wsum[0] + wsum[1] + wsum[2] + wsum[3];
}

__global__ void scan2_kernel(int* __restrict__ blockSums, int* __restrict__ row_start,
                             int nb, int n) {
    int lane = threadIdx.x & 63;
    int v = (lane < nb) ? blockSums[lane] : 0;
    int inc = v;
    #pragma unroll
    for (int off = 1; off < 64; off <<= 1) {
        int t = __shfl_up(inc, off);
        if (lane >= off) inc += t;
    }
    if (lane < nb) blockSums[lane] = inc - v;
    if (lane == 63) row_start[n] = inc;
}

__global__ __launch_bounds__(256) void scan3_kernel(const int* __restrict__ deg,
                                                    const int* __restrict__ blockSums,
                                                    int* __restrict__ row_start,
                                                    int* __restrict__ cursor,
                                                    float* __restrict__ invdeg, int n) {
    __shared__ int wsum[4];
    int tid = threadIdx.x, lane = tid & 63, wave = tid >> 6;
    int carry = blockSums[blockIdx.x];
    int idx0 = blockIdx.x * SCAN_CHUNK + tid * 8;
    int v[8], pre[8];
    int s = 0;
    #pragma unroll
    for (int u = 0; u < 8; ++u) {
        int id = idx0 + u;
        int d = (id < n) ? deg[id] : 0;
        v[u] = d;
        pre[u] = s;
        s += (d + 7) & ~7;
    }
    int inc = s;
    #pragma unroll
    for (int off = 1; off < 64; off <<= 1) {
        int t = __shfl_up(inc, off);
        if (lane >= off) inc += t;
    }
    if (lane == 63) wsum[wave] = inc;
    __syncthreads();
    int woff = 0;
    for (int w2 = 0; w2 < wave; ++w2) woff += wsum[w2];
    int eb = carry + woff + inc - s;
    #pragma unroll
    for (int u = 0; u < 8; ++u) {
        int id = idx0 + u;
        if (id < n) {
            int rs = eb + pre[u];
            row_start[id] = rs;
            cursor[id] = rs;
            invdeg[id] = 1.0f / fmaxf((float)v[u], 1.0f);
        }
    }
}

// SoA record: basisB[pos] = {b0|b1<<16, b2|b3<<16} bf16, metaB[pos] = src | i00<<20
__global__ void scatter_kernel(const int* __restrict__ ei, const float* __restrict__ pseudo,
                               const float* __restrict__ invdeg, int* __restrict__ cursor,
                               uint2* __restrict__ basisB, unsigned* __restrict__ metaB, int E) {
    int e = blockIdx.x * blockDim.x + threadIdx.x;
    if (e >= E) return;
    int src = ei[e], dst = ei[E + e];
    float p0 = pseudo[2 * e], p1 = pseudo[2 * e + 1];
    float v0 = fminf(fmaxf(p0, 0.f), 1.f) * 4.f;
    float v1 = fminf(fmaxf(p1, 0.f), 1.f) * 4.f;
    int k00 = min((int)floorf(v0), 3);
    int k01 = min((int)floorf(v1), 3);
    float f0 = v0 - (float)k00, f1 = v1 - (float)k01;
    float g0 = 1.f - f0, g1 = 1.f - f1;
    float sc = invdeg[dst];
    int i00 = k00 * 5 + k01;
    int pos = atomicAdd(&cursor[dst], 1);
    uint2 b;
    b.x = (unsigned)f2bf(g0 * g1 * sc) | ((unsigned)f2bf(g0 * f1 * sc) << 16);
    b.y = (unsigned)f2bf(f0 * g1 * sc) | ((unsigned)f2bf(f0 * f1 * sc) << 16);
    basisB[pos] = b;
    metaB[pos] = (unsigned)src | ((unsigned)i00 << 20);
}

// Fragment-major Wt: WtF[((s*NT + nt)*64 + lane)*8 + e] = W_logical[o][kk]
template <int Cin, int Cout, int KW>
__global__ void wprep_kernel(const float* __restrict__ W, const float* __restrict__ root,
                             unsigned short* __restrict__ WtF) {
    constexpr int NT = Cout / 16;
    int idx = blockIdx.x * 256 + threadIdx.x;
    if (idx >= Cout * KW) return;
    int e = idx & 7;
    int lane = (idx >> 3) & 63;
    int sn = idx >> 9;
    int s = sn / NT, nt = sn - s * NT;
    int r16 = lane & 15, g8 = lane >> 4;
    int o = nt * 16 + r16;
    int kk = s * 32 + g8 * 8 + e;
    float v = 0.f;
    if (kk < 26 * Cin) {
        int k = kk / Cin, i = kk - k * Cin;
        v = (k < 25) ? W[(k * Cin + i) * Cout + o] : root[i * Cout + o];
    }
    WtF[idx] = f2bf(v);
}

// ---------------------------------------------------------------- fused layer

template <int Cin, int Cout, bool F32IN>
__global__ __launch_bounds__(512, 4) void layer_kernel(
        const void* __restrict__ xin_, const unsigned short* __restrict__ WtF,
        const float* __restrict__ bias, const int* __restrict__ row_start,
        const int* __restrict__ row_end, const uint2* __restrict__ basisG,
        const unsigned* __restrict__ metaG, unsigned short* __restrict__ xout,
        int nNodes) {
    constexpr int T = 16;
    constexpr int SLICES = (26 * Cin + 31) / 32;
    constexpr int NPAIR = (SLICES + 1) / 2;
    constexpr int ST = NPAIR * 72 + 8;          // ushort elems per node row
    constexpr int MT = (Cin + 15) / 16;
    constexpr int NT_B = Cout / 16;
    constexpr int W8 = 8 / NT_B;
    constexpr int RS = Cout + 4;
    constexpr int BSZ = 32 * 34;                // ushorts per wave B matrix
    constexpr int DEPTH = (MT <= 2) ? 2 : 1;    // gather prefetch depth

    __shared__ __align__(16) unsigned short acc[T * ST];
    __shared__ __align__(16) unsigned short Ball[8 * BSZ];

    const int tid = threadIdx.x;
    const int node0 = blockIdx.x * T;
    const int wave = tid >> 6, lane = tid & 63;
    const int r16 = lane & 15, g8 = lane >> 4;   // g8 in 0..3
    const float* xf = (const float*)xin_;
    const unsigned short* xb = (const unsigned short*)xin_;

    // ---- zero acc
    {
        uint4 z = make_uint4(0u, 0u, 0u, 0u);
        for (int p = tid; p < T * ST / 8; p += 512) ((uint4*)acc)[p] = z;
    }
    __syncthreads();
    // ---- self features at k=25
    for (int p = tid; p < T * Cin; p += 512) {
        int t = p / Cin, i = p - t * Cin;
        int n = node0 + t;
        if (n < nNodes) {
            unsigned short v = F32IN ? f2bf(xf[n * Cin + i]) : xb[n * Cin + i];
            acc[t * ST + pairaddr(25 * Cin + i)] = v;
        }
    }

    // ---- stage-1: 2 nodes per wave, pipelined 32-edge virtual chunks
    unsigned short* Bw = Ball + wave * BSZ;
    {
        const int t0 = wave, t1 = wave + 8;
        const int na = node0 + t0, nb = node0 + t1;
        int eb0 = 0, ee0 = 0, eb1 = 0, ee1 = 0;
        if (na < nNodes) { eb0 = row_start[na]; ee0 = row_end[na]; }
        if (nb < nNodes) { eb1 = row_start[nb]; ee1 = row_end[nb]; }
        const int nc0 = (ee0 - eb0 + 31) >> 5;
        const int nc1 = (ee1 - eb1 + 31) >> 5;
        const int TC = nc0 + nc1;

        if (TC > 0) {
            auto info = [&](int vc, int& base, int& ee) {
                bool first = vc < nc0;
                int c = first ? vc : vc - nc0;
                base = (first ? eb0 : eb1) + (c << 5);
                ee = first ? ee0 : ee1;
            };
            auto loadMeta = [&](int vc, uint4& a, uint4& b) {
                int base, ee;
                info(vc, base, ee);
                const uint4* p = (const uint4*)(metaG + base + g8 * 8);
                a = p[0];
                b = p[1];
            };
            auto gatherA = [&](const uint4& a, const uint4& b, bf16x8* af) {
                int s[8];
                s[0] = a.x & 0xFFFFF; s[1] = a.y & 0xFFFFF;
                s[2] = a.z & 0xFFFFF; s[3] = a.w & 0xFFFFF;
                s[4] = b.x & 0xFFFFF; s[5] = b.y & 0xFFFFF;
                s[6] = b.z & 0xFFFFF; s[7] = b.w & 0xFFFFF;
                #pragma unroll
                for (int mt = 0; mt < MT; ++mt) {
                    int col = (Cin >= 16) ? (mt * 16 + r16) : (r16 & (Cin - 1));
                    #pragma unroll
                    for (int j = 0; j < 8; ++j)
                        af[mt][j] = (short)(F32IN ? f2bf(xf[s[j] * Cin + col])
                                                  : xb[s[j] * Cin + col]);
                }
            };
            auto loadScat = [&](int vc, unsigned& bx, unsigned& by, int& i00,
                                bool& valid) {
                int base, ee;
                info(vc, base, ee);
                int e = base + (lane & 31);
                valid = (lane < 32) && (e < ee);
                uint2 bb = basisG[e];
                unsigned mm = metaG[e];
                bx = bb.x;
                by = bb.y;
                i00 = (int)(mm >> 20);
            };

            f32x4 d[MT][2];
            #pragma unroll
            for (int mt = 0; mt < MT; ++mt)
                #pragma unroll
                for (int nt = 0; nt < 2; ++nt)
                    d[mt][nt] = (f32x4){0.f, 0.f, 0.f, 0.f};

            auto spill = [&](int t) {
                #pragma unroll
                for (int nt = 0; nt < 2; ++nt) {
                    int k = nt * 16 + r16;
                    if (k < 25) {
                        #pragma unroll
                        for (int mt = 0; mt < MT; ++mt) {
                            int ch0 = mt * 16 + g8 * 4;
                            if (ch0 < Cin) {
                                unsigned p0 = (unsigned)f2bf(d[mt][nt][0]) |
                                              ((unsigned)f2bf(d[mt][nt][1]) << 16);
                                unsigned p1 = (unsigned)f2bf(d[mt][nt][2]) |
                                              ((unsigned)f2bf(d[mt][nt][3]) << 16);
                                *(uint2*)&acc[t * ST + pairaddr(k * Cin + ch0)] =
                                    make_uint2(p0, p1);
                            }
                        }
                    }
                }
                #pragma unroll
                for (int mt = 0; mt < MT; ++mt)
                    #pragma unroll
                    for (int nt = 0; nt < 2; ++nt)
                        d[mt][nt] = (f32x4){0.f, 0.f, 0.f, 0.f};
            };

            auto computeB = [&](unsigned bxC, unsigned byC, int i00C, bool vldC,
                                bf16x8* af) {
                uint4 z = make_uint4(0u, 0u, 0u, 0u);
                uint4* b4 = (uint4*)Bw;
                #pragma unroll
                for (int q = 0; q < 3; ++q) {
                    int p = lane + q * 64;
                    if (p < BSZ / 8) b4[p] = z;
                }
                if (vldC) {
                    int le = lane & 31;
                    Bw[le * 34 + i00C]     = (unsigned short)(bxC & 0xFFFFu);
                    Bw[le * 34 + i00C + 1] = (unsigned short)(bxC >> 16);
                    Bw[le * 34 + i00C + 5] = (unsigned short)(byC & 0xFFFFu);
                    Bw[le * 34 + i00C + 6] = (unsigned short)(byC >> 16);
                }
                #pragma unroll
                for (int nt = 0; nt < 2; ++nt) {
                    bf16x8 bfr;
                    #pragma unroll
                    for (int j = 0; j < 8; ++j)
                        bfr[j] = (short)Bw[(g8 * 8 + j) * 34 + nt * 16 + r16];
                    #pragma unroll
                    for (int mt = 0; mt < MT; ++mt)
                        d[mt][nt] = __builtin_amdgcn_mfma_f32_16x16x32_bf16(
                            af[mt], bfr, d[mt][nt], 0, 0, 0);
                }
            };

            if constexpr (DEPTH == 2) {
                // 2-deep gather pipeline (L1/L2)
                uint4 m2a, m2b;
                bf16x8 af0[MT], af1[MT], af2[MT];
                unsigned bxC, byC, bxN, byN;
                int i00C, i00N;
                bool vldC, vldN;
                {
                    uint4 a, b;
                    loadMeta(0, a, b);
                    gatherA(a, b, af0);
                    if (TC > 1) {
                        loadMeta(1, a, b);
                        gatherA(a, b, af1);
                    }
                    if (TC > 2) loadMeta(2, m2a, m2b);
                }
                loadScat(0, bxC, byC, i00C, vldC);

                for (int vc = 0; vc < TC; ++vc) {
                    if (vc + 2 < TC) {
                        gatherA(m2a, m2b, af2);
                        if (vc + 3 < TC) loadMeta(vc + 3, m2a, m2b);
                    }
                    if (vc + 1 < TC) loadScat(vc + 1, bxN, byN, i00N, vldN);

                    computeB(bxC, byC, i00C, vldC, af0);
                    if (vc == nc0 - 1) spill(t0);

                    #pragma unroll
                    for (int mt = 0; mt < MT; ++mt) {
                        af0[mt] = af1[mt];
                        af1[mt] = af2[mt];
                    }
                    bxC = bxN; byC = byN; i00C = i00N; vldC = vldN;
                }
                if (nc1 > 0) spill(t1);
            } else {
                // 1-deep pipeline (L3)
                uint4 nA, nB;
                bf16x8 afC[MT], afN[MT];
                unsigned bxC, byC, bxN, byN;
                int i00C, i00N;
                bool vldC, vldN;
                {
                    uint4 a, b;
                    loadMeta(0, a, b);
                    gatherA(a, b, afC);
                }
                loadScat(0, bxC, byC, i00C, vldC);
                if (TC > 1) loadMeta(1, nA, nB);

                for (int vc = 0; vc < TC; ++vc) {
                    if (vc + 1 < TC) {
                        gatherA(nA, nB, afN);
                        if (vc + 2 < TC) loadMeta(vc + 2, nA, nB);
                        loadScat(vc + 1, bxN, byN, i00N, vldN);
                    }

                    computeB(bxC, byC, i00C, vldC, afC);
                    if (vc == nc0 - 1) spill(t0);

                    #pragma unroll
                    for (int mt = 0; mt < MT; ++mt) afC[mt] = afN[mt];
                    bxC = bxN; byC = byN; i00C = i00N; vldC = vldN;
                }
                if (nc1 > 0) spill(t1);
            }
        }
    }
    __syncthreads();

    // ---- phase B: acc x WtF (fragment-major, contiguous 1KB loads), K-split W8
    const int q = wave / NT_B;
    const int nt = wave % NT_B;
    f32x4 db = {0.f, 0.f, 0.f, 0.f};
    {
        const unsigned short* ap = acc + r16 * ST;
        for (int s = q; s < SLICES; s += W8) {
            bf16x8 a8 = *(const bf16x8*)(ap + (s >> 1) * 72 + (s & 1) * 32 + g8 * 8);
            bf16x8 b8 = *(const bf16x8*)(WtF + ((size_t)(s * NT_B + nt) * 64 + lane) * 8);
            db = __builtin_amdgcn_mfma_f32_16x16x32_bf16(a8, b8, db, 0, 0, 0);
        }
    }
    __syncthreads();
    float* red = (float*)acc;
    if (q > 0) {
        #pragma unroll
        for (int j = 0; j < 4; ++j)
            red[((q - 1) * T + g8 * 4 + j) * RS + nt * 16 + r16] = db[j];
    }
    __syncthreads();
    if (q == 0) {
        const int o = nt * 16 + r16;
        const float bo = bias[o];
        #pragma unroll
        for (int j = 0; j < 4; ++j) {
            int row = g8 * 4 + j;
            int n = node0 + row;
            if (n < nNodes) {
                float v = db[j] + bo;
                #pragma unroll
                for (int q2 = 1; q2 < W8; ++q2)
                    v += red[((q2 - 1) * T + row) * RS + o];
                v = (v > 0.f) ? v : expm1f(v);
                xout[n * Cout + o] = f2bf(v);
            }
        }
    }
}

// ---------------------------------------------------------------- pooling + head

__global__ void pool_kernel(const unsigned short* __restrict__ h, const int* __restrict__ batch,
                            float* __restrict__ pooled, float* __restrict__ cnt, int n) {
    int gw = (blockIdx.x * blockDim.x + threadIdx.x) >> 6;
    int lane = threadIdx.x & 63;
    int nw = (gridDim.x * blockDim.x) >> 6;
    int per = (n + nw - 1) / nw;
    int n0 = gw * per, n1 = min(n0 + per, n);
    if (n0 >= n1) return;
    int cur = batch[n0];
    float s = 0.f, c = 0.f;
    int nn = n0;
    while (nn < n1) {
        int m = min(4, n1 - nn);
        float v[4];
        int b[4];
        #pragma unroll
        for (int u = 0; u < 4; ++u) {
            int id = (u < m) ? (nn + u) : (n1 - 1);
            b[u] = batch[id];
            v[u] = bf2f(h[(size_t)id * 64 + lane]);
        }
        #pragma unroll
        for (int u = 0; u < 4; ++u) {
            if (u < m) {
                if (b[u] != cur) {
                    atomicAdd(&pooled[cur * 64 + lane], s);
                    if (lane == 0) atomicAdd(&cnt[cur], c);
                    s = 0.f; c = 0.f; cur = b[u];
                }
                s += v[u];
                c += 1.f;
            }
        }
        nn += 4;
    }
    atomicAdd(&pooled[cur * 64 + lane], s);
    if (lane == 0) atomicAdd(&cnt[cur], c);
}

// One wave per graph: lane j<30 computes logit_j; shfl reductions for log-softmax.
__global__ __launch_bounds__(64) void head_kernel(const float* __restrict__ pooled,
                                                  const float* __restrict__ cnt,
                                                  const float* __restrict__ fcw,
                                                  const float* __restrict__ fcb,
                                                  float* __restrict__ outp, int G) {
    int g = blockIdx.x;
    int j = threadIdx.x;
    if (g >= G) return;
    float inv = 1.f / fmaxf(cnt[g], 1.f);
    float s = -1e30f;
    if (j < 30) {
        s = fcb[j];
        for (int i = 0; i < 64; ++i)
            s += pooled[g * 64 + i] * inv * fcw[i * 30 + j];
    }
    float m = s;
    #pragma unroll
    for (int off = 1; off < 64; off <<= 1) m = fmaxf(m, __shfl_xor(m, off));
    float e = (j < 30) ? expf(s - m) : 0.f;
    float lse = e;
    #pragma unroll
    for (int off = 1; off < 64; off <<= 1) lse += __shfl_xor(lse, off);
    lse = logf(lse);
    if (j < 30) outp[g * 30 + j] = s - m - lse;
}

// ---------------------------------------------------------------- launch

extern "C" void kernel_launch(void* const* d_in, const int* in_sizes, int n_in,
                              void* d_out, int out_size, void* d_ws, size_t ws_size,
                              hipStream_t stream) {
    const float* x = (const float*)d_in[0];
    const int* ei = (const int*)d_in[1];
    const float* ps = (const float*)d_in[2];
    const int* batch = (const int*)d_in[3];
    const float *w1 = (const float*)d_in[4], *r1 = (const float*)d_in[5], *b1 = (const float*)d_in[6];
    const float *w2 = (const float*)d_in[7], *r2 = (const float*)d_in[8], *b2 = (const float*)d_in[9];
    const float *w3 = (const float*)d_in[10], *r3 = (const float*)d_in[11], *b3 = (const float*)d_in[12];
    const float *fcw = (const float*)d_in[13], *fcb = (const float*)d_in[14];
    float* outp = (float*)d_out;

    const int nN = in_sizes[0] / 8;  // 50000
    const int E = in_sizes[1] / 2;   // 800000
    const int G = out_size / 30;     // 128
    const int EP = E + 8 * nN + 64;  // padded edge capacity
    const int NSB = (nN + SCAN_CHUNK - 1) / SCAN_CHUNK;   // scan blocks (25 <= 64)

    char* wsb = (char*)d_ws;
    size_t off = 0;
    auto alloc = [&](size_t b) -> char* {
        char* p = wsb + off;
        off = (off + b + 255) & ~(size_t)255;
        return p;
    };
    int* deg = (int*)alloc((size_t)nN * 4);
    int* row_start = (int*)alloc((size_t)(nN + 1) * 4);
    int* cursor = (int*)alloc((size_t)nN * 4);
    float* invdeg = (float*)alloc((size_t)nN * 4);
    int* blockSums = (int*)alloc((size_t)64 * 4);
    uint2* basisB = (uint2*)alloc((size_t)EP * 8);
    unsigned* metaB = (unsigned*)alloc((size_t)EP * 4);
    unsigned short* wt1 = (unsigned short*)alloc((size_t)32 * 224 * 2);
    unsigned short* wt2 = (unsigned short*)alloc((size_t)64 * 832 * 2);
    unsigned short* wt3 = (unsigned short*)alloc((size_t)64 * 1664 * 2);
    unsigned short* h1 = (unsigned short*)alloc((size_t)nN * 32 * 2);
    unsigned short* h2 = (unsigned short*)alloc((size_t)nN * 64 * 2);
    unsigned short* h3 = (unsigned short*)alloc((size_t)nN * 64 * 2);
    float* pooled = (float*)alloc((size_t)G * 64 * 4);
    float* cnt = (float*)alloc((size_t)G * 4);
    (void)ws_size;

    hipMemsetAsync(deg, 0, (size_t)nN * 4, stream);
    hipMemsetAsync(metaB, 0, (size_t)EP * 4, stream);   // pad metas -> src 0 (safe)
    hipMemsetAsync(pooled, 0, (size_t)G * 64 * 4, stream);
    hipMemsetAsync(cnt, 0, (size_t)G * 4, stream);

    int ebk = (E + 255) / 256;
    hist_kernel<<<ebk, 256, 0, stream>>>(ei, deg, E);
    scan1_kernel<<<NSB, 256, 0, stream>>>(deg, blockSums, nN);
    scan2_kernel<<<1, 64, 0, stream>>>(blockSums, row_start, NSB, nN);
    scan3_kernel<<<NSB, 256, 0, stream>>>(deg, blockSums, row_start, cursor, invdeg, nN);
    scatter_kernel<<<ebk, 256, 0, stream>>>(ei, ps, invdeg, cursor, basisB, metaB, E);
    wprep_kernel<8, 32, 224><<<(32 * 224 + 255) / 256, 256, 0, stream>>>(w1, r1, wt1);
    wprep_kernel<32, 64, 832><<<(64 * 832 + 255) / 256, 256, 0, stream>>>(w2, r2, wt2);
    wprep_kernel<64, 64, 1664><<<(64 * 1664 + 255) / 256, 256, 0, stream>>>(w3, r3, wt3);

    int nb = (nN + 15) / 16;
    layer_kernel<8, 32, true><<<nb, 512, 0, stream>>>(
        x, wt1, b1, row_start, cursor, basisB, metaB, h1, nN);
    layer_kernel<32, 64, false><<<nb, 512, 0, stream>>>(
        h1, wt2, b2, row_start, cursor, basisB, metaB, h2, nN);
    layer_kernel<64, 64, false><<<nb, 512, 0, stream>>>(
        h2, wt3, b3, row_start, cursor, basisB, metaB, h3, nN);

    pool_kernel<<<128, 256, 0, stream>>>(h3, batch, pooled, cnt, nN);
    head_kernel<<<G, 64, 0, stream>>>(pooled, cnt, fcw, fcb, outp, G);
}